// Round 1
// baseline (96.016 us; speedup 1.0000x reference)
//
#include <hip/hip_runtime.h>
#include <math.h>

// Problem constants (B,H,N,D) = (2,16,4096,128), fp32 in/out.
static constexpr int kB  = 2;
static constexpr int kH  = 16;
static constexpr int kN  = 4096;
static constexpr int kD  = 128;
static constexpr int kBH = kB * kH;      // 32 channel-groups
static constexpr int kD4 = kD / 4;       // 32 float4 per row

// ---------------------------------------------------------------------------
// Pass 1: per-(bh,chunk) inclusive cumsum of w = sigmoid(q*k+g)*v along time.
// 32 lanes per task, each lane owns one float4 slice of D. Writes the
// within-chunk inclusive scan to out and the chunk total to sums[bh][c][d].
// ---------------------------------------------------------------------------
template <int C>
__global__ __launch_bounds__(256) void gla_pass1(
    const float4* __restrict__ q, const float4* __restrict__ k,
    const float4* __restrict__ v, const float4* __restrict__ g,
    float4* __restrict__ out, float4* __restrict__ sums)
{
    constexpr int T = kN / C;
    const int gtid = blockIdx.x * 256 + threadIdx.x;
    const int lane = gtid & (kD4 - 1);      // d-quad 0..31
    const int task = gtid >> 5;             // bh*C + c  (exact grid)
    const int bh   = task / C;              // C is pow2 -> shift
    const int c    = task & (C - 1);

    size_t base = ((size_t)bh * kN + (size_t)c * T) * kD4 + lane;
    float4 acc = make_float4(0.f, 0.f, 0.f, 0.f);

#pragma unroll 4
    for (int t = 0; t < T; ++t) {
        const size_t idx = base + (size_t)t * kD4;
        const float4 q4 = q[idx];
        const float4 k4 = k[idx];
        const float4 g4 = g[idx];
        const float4 v4 = v[idx];
        acc.x += v4.x / (1.0f + expf(-(q4.x * k4.x + g4.x)));
        acc.y += v4.y / (1.0f + expf(-(q4.y * k4.y + g4.y)));
        acc.z += v4.z / (1.0f + expf(-(q4.z * k4.z + g4.z)));
        acc.w += v4.w / (1.0f + expf(-(q4.w * k4.w + g4.w)));
        out[idx] = acc;
    }
    sums[(size_t)task * kD4 + lane] = acc;
}

// ---------------------------------------------------------------------------
// Pass 2: in-place exclusive scan over the C chunk totals for each (bh,d)
// channel. One block per bh, one thread per d. Tiny (2 MB traffic).
// ---------------------------------------------------------------------------
template <int C>
__global__ void gla_pass2(float* __restrict__ sums)
{
    const int bh = blockIdx.x;
    const int d  = threadIdx.x;           // 0..127
    size_t base = (size_t)bh * C * kD + d;
    float run = 0.f;
#pragma unroll
    for (int c = 0; c < C; ++c) {
        const size_t i = base + (size_t)c * kD;
        const float t = sums[i];
        sums[i] = run;
        run += t;
    }
}

// ---------------------------------------------------------------------------
// Pass 3: out[bh][t][d] += sums[bh][t/T][d]. float4 per thread.
// ---------------------------------------------------------------------------
template <int C>
__global__ __launch_bounds__(256) void gla_pass3(
    float4* __restrict__ out, const float4* __restrict__ sums)
{
    constexpr int T = kN / C;
    const int gtid = blockIdx.x * 256 + threadIdx.x;
    const int lane = gtid & (kD4 - 1);
    const int nt   = gtid >> 5;           // bh*N + t   (kD4 == 32)
    const int bh   = nt / kN;
    const int t    = nt & (kN - 1);
    const int c    = t / T;               // pow2 -> shift

    const float4 add = sums[((size_t)bh * C + c) * kD4 + lane];
    float4 o = out[gtid];
    o.x += add.x; o.y += add.y; o.z += add.z; o.w += add.w;
    out[gtid] = o;
}

// ---------------------------------------------------------------------------
template <int C>
static void launch_all(const float4* q, const float4* k, const float4* v,
                       const float4* g, float4* out, void* ws,
                       hipStream_t stream)
{
    const int tasks    = kBH * C;                 // 32-lane tasks
    const int threads1 = tasks * 32;
    gla_pass1<C><<<threads1 / 256, 256, 0, stream>>>(q, k, v, g, out,
                                                     (float4*)ws);
    gla_pass2<C><<<kBH, kD, 0, stream>>>((float*)ws);
    const int threads3 = kBH * kN * kD4;
    gla_pass3<C><<<threads3 / 256, 256, 0, stream>>>(out, (const float4*)ws);
}

extern "C" void kernel_launch(void* const* d_in, const int* in_sizes, int n_in,
                              void* d_out, int out_size, void* d_ws,
                              size_t ws_size, hipStream_t stream)
{
    const float4* q = (const float4*)d_in[0];
    const float4* k = (const float4*)d_in[1];
    const float4* v = (const float4*)d_in[2];
    const float4* g = (const float4*)d_in[3];
    float4* out = (float4*)d_out;

    constexpr size_t need128 = (size_t)kBH * 128 * kD * sizeof(float); // 2 MiB
    if (ws_size >= need128) {
        launch_all<128>(q, k, v, g, out, d_ws, stream);
    } else {
        // Fallback: smaller chunk-sum buffer (512 KiB).
        launch_all<32>(q, k, v, g, out, d_ws, stream);
    }
}